// Round 7
// baseline (150.921 us; speedup 1.0000x reference)
//
#include <hip/hip_runtime.h>

#define D_MODEL 1024
#define D_HEAD  64
#define SEQ     4096
#define BATCH   4
#define M_TOT   (BATCH * SEQ)          // 16384
#define LOG2E   1.44269504088896f
#define MFIX_L2 17.3123404906676f      // 12.0 * log2(e) — fixed softmax max
#define CHUNK   16                     // k-tiles per attn block

typedef __bf16 bf16;
typedef bf16  bf16x8 __attribute__((ext_vector_type(8)));
typedef bf16  bf16x4v __attribute__((ext_vector_type(4)));
typedef float f32x4  __attribute__((ext_vector_type(4)));

#define MFMA(a, b, c) __builtin_amdgcn_mfma_f32_16x16x32_bf16(a, b, c, 0, 0, 0)

// Full phase barrier for DMA-staged pipelines: drains the global_load_lds
// queue (vmcnt) so the staged LDS tile is cross-wave visible, then barriers.
// sched_barrier(0) fences stop hipcc hoisting ds_reads across it (rule #18).
__device__ __forceinline__ void phase_barrier() {
    __builtin_amdgcn_sched_barrier(0);
    asm volatile("s_waitcnt vmcnt(0)" ::: "memory");
    __builtin_amdgcn_s_barrier();
    __builtin_amdgcn_sched_barrier(0);
}

// global -> LDS DMA, 16 bytes per lane. Dest is wave-uniform base + lane*16
// (linear); per-lane GLOBAL address carries any swizzle (m173 pattern).
__device__ __forceinline__ void gld16(const void* g, void* l) {
    __builtin_amdgcn_global_load_lds(
        (const __attribute__((address_space(1))) void*)g,
        (__attribute__((address_space(3))) void*)l, 16, 0, 0);
}

// Workspace layout (bytes):
//   qkv   bf16 [3][M_TOT][64]   @ 0         (6,291,456)  (V section unused)
//   o_buf f32  [M_TOT][64]      @ 6291456   (4,194,304)
//   l_buf f32  [M_TOT]          @ 10485760  (65,536)
//   Wt    bf16 [3][64][1024]    @ 10551296  (393,216)
//   vt    bf16 [B][64][SEQ]     @ 10944512  (2,097,152)   V transposed
#define QKV_OFF  0
#define OBUF_OFF 6291456
#define LBUF_OFF 10485760
#define WT_OFF   10551296
#define VT_OFF   10944512

// ---------------------------------------------------------------------------
// Prep. Blocks 0..47: transpose+cast W (fp32 [1024][64]) -> Wt (bf16
// [wm*64+n][1024]) via LDS tile. Blocks 48..: zero o_buf + l_buf.
// ---------------------------------------------------------------------------
__global__ void prep_kernel(const float* __restrict__ Wq, const float* __restrict__ Wk,
                            const float* __restrict__ Wv, bf16* __restrict__ Wt,
                            float4* __restrict__ zp, int n4)
{
    const int bx = blockIdx.x;
    const int t  = threadIdx.x;
    if (bx < 48) {
        __shared__ bf16 tr[64][72];                    // [n][k] tile, padded
        const int wm = bx >> 4, kt = bx & 15, k0 = kt * 64;
        const float* W = (wm == 0) ? Wq : (wm == 1) ? Wk : Wv;
        const int kr = t >> 2, nb = (t & 3) * 16;
        #pragma unroll
        for (int j = 0; j < 4; j++) {
            float4 wrow = *(const float4*)(W + (size_t)(k0 + kr) * D_HEAD + nb + j * 4);
            tr[nb + j * 4 + 0][kr] = (bf16)wrow.x;
            tr[nb + j * 4 + 1][kr] = (bf16)wrow.y;
            tr[nb + j * 4 + 2][kr] = (bf16)wrow.z;
            tr[nb + j * 4 + 3][kr] = (bf16)wrow.w;
        }
        __syncthreads();
        const int n = t >> 2, kc = (t & 3) * 8;
        bf16* dst = Wt + (size_t)(wm * 64 + n) * D_MODEL + k0;
        #pragma unroll
        for (int h = 0; h < 2; h++) {
            bf16x8 v;
            #pragma unroll
            for (int j = 0; j < 8; j++) v[j] = tr[n][kc + h * 32 + j];
            *(bf16x8*)(dst + kc + h * 32) = v;
        }
    } else {
        int i = (bx - 48) * 256 + t;
        if (i < n4) zp[i] = float4{0.f, 0.f, 0.f, 0.f};
    }
}

// ---------------------------------------------------------------------------
// Fused QKV projection v11 (unchanged; round-6 verified — dropped out of the
// top-5). T3 minimum-2-phase with global_load_lds DMA staging, T2 XOR
// swizzle in both-sides form, BM=32 BN=192 BK=64, grid 512, 4 waves.
// ---------------------------------------------------------------------------
__global__ __launch_bounds__(256, 2) void proj_kernel(
    const float* __restrict__ x, const bf16* __restrict__ Wt,
    bf16* __restrict__ qkv, bf16* __restrict__ vt)
{
    __shared__ __align__(16) char Al[2][32 * 256];   // fp32 [32 r][256 B] x2 = 16 KB
    __shared__ __align__(16) char Bl[2][192 * 128];  // bf16 [192 n][128 B] x2 = 48 KB

    const int t    = threadIdx.x;
    const int wv   = t >> 6;            // wave = col group (48 cols)
    const int lane = t & 63;
    const int quad = lane >> 4;
    const int l15  = lane & 15;
    const int row0 = blockIdx.x * 32;

    const char* xb = (const char*)x;
    const char* wb = (const char*)Wt;

    f32x4 acc[6] = {};                  // acc[rg*3+j]

    // ---- DMA staging (linear dest, swizzled source) ----
    auto stageA = [&](int bsel, int step) {
        #pragma unroll
        for (int i = 0; i < 2; i++) {
            const int s  = wv * 2 + i;          // 1 KB segment
            const int r  = s * 4 + (lane >> 4); // A row this lane feeds
            const int cs = ((lane & 15) * 16) ^ ((r & 7) << 4);
            const void* g = xb + (size_t)(row0 + r) * 4096 + step * 256 + cs;
            gld16(g, (char*)Al[bsel] + s * 1024);
        }
    };
    auto stageB = [&](int bsel, int step) {
        #pragma unroll
        for (int i = 0; i < 6; i++) {
            const int s  = wv * 6 + i;
            const int n  = s * 8 + (lane >> 3);
            const int cs = ((lane & 7) * 16) ^ ((n & 7) << 4);
            const void* g = wb + (size_t)n * 2048 + step * 128 + cs;
            gld16(g, (char*)Bl[bsel] + s * 1024);
        }
    };

    auto cvt8 = [](float4 lo, float4 hi) {
        bf16x8 r;
        r[0] = (bf16)lo.x; r[1] = (bf16)lo.y; r[2] = (bf16)lo.z; r[3] = (bf16)lo.w;
        r[4] = (bf16)hi.x; r[5] = (bf16)hi.y; r[6] = (bf16)hi.z; r[7] = (bf16)hi.w;
        return r;
    };

    // ---- compute one BK=64 tile from LDS buffer bsel ----
    auto compute = [&](int bsel) {
        const char* Ab = Al[bsel];
        const char* Bb = Bl[bsel];
        #pragma unroll
        for (int ks = 0; ks < 2; ks++) {        // two K=32 slices
            bf16x8 afr[2];
            #pragma unroll
            for (int rg = 0; rg < 2; rg++) {
                const int r  = rg * 16 + l15;
                const int o  = ks * 128 + quad * 32;
                const int m  = (r & 7) << 4;
                float4 lo = *(const float4*)(Ab + r * 256 + (o ^ m));
                float4 hi = *(const float4*)(Ab + r * 256 + ((o + 16) ^ m));
                afr[rg] = cvt8(lo, hi);
            }
            #pragma unroll
            for (int j = 0; j < 3; j++) {
                const int n  = wv * 48 + j * 16 + l15;
                const int o  = ks * 64 + quad * 16;
                bf16x8 bfrg = *(const bf16x8*)(Bb + n * 128 + (o ^ ((n & 7) << 4)));
                acc[0 * 3 + j] = MFMA(afr[0], bfrg, acc[0 * 3 + j]);
                acc[1 * 3 + j] = MFMA(afr[1], bfrg, acc[1 * 3 + j]);
            }
        }
    };

    // ---- 2-phase K loop (16 steps of BK=64) ----
    stageA(0, 0);
    stageB(0, 0);
    phase_barrier();                    // tile 0 staged

    int buf = 0;
    for (int s = 0; s < 16; s++) {
        if (s + 1 < 16) {               // issue next tile's DMAs first
            stageA(buf ^ 1, s + 1);
            stageB(buf ^ 1, s + 1);
        }
        compute(buf);                   // hides the DMA latency
        phase_barrier();                // next tile ready; WAR-safe
        buf ^= 1;
    }

    // epilogue (v8-verified): C row = quad*4 + r, col = l15
    const int bb = row0 >> 12, s0 = row0 & (SEQ - 1);
    #pragma unroll
    for (int rg = 0; rg < 2; rg++)
        #pragma unroll
        for (int j = 0; j < 3; j++) {
            const int col = wv * 48 + j * 16 + l15;   // wm uniform per (wv,j)
            const int wm = col >> 6, h = col & 63;
            if (wm == 2) {
                bf16x4v vv;
                #pragma unroll
                for (int r = 0; r < 4; r++)
                    vv[r] = (bf16)acc[rg * 3 + j][r];
                *(bf16x4v*)(vt + ((size_t)bb * D_HEAD + h) * SEQ +
                            s0 + rg * 16 + quad * 4) = vv;
            } else {
                const float sc = (wm == 0) ? 0.125f : 1.0f;
                bf16* outp = qkv + (size_t)wm * M_TOT * D_HEAD;
                #pragma unroll
                for (int r = 0; r < 4; r++) {
                    const int row = row0 + rg * 16 + quad * 4 + r;
                    outp[(size_t)row * D_HEAD + h] =
                        (bf16)(acc[rg * 3 + j][r] * sc);
                }
            }
        }
}

// ---------------------------------------------------------------------------
// Split-K causal flash attention v7 = v6 with K/V staging moved to
// global_load_lds DMA (the proj v11 recipe, round-6 verified):
//   * Per tile each wave issues 4 gld16 (K: 2 segments, V: 2 segments,
//     1 KB each). Linear LDS dest + INVERSE-swizzled global source gives a
//     byte-identical LDS image to the old store_kv (LDS[r][c] = G[r][c^swz]),
//     so every kaddr read and the MFMA fragment layout are unchanged.
//   * Schedule: issue next tile's DMAs -> compute (QK^T+softmax+shfl+PV,
//     covers the L2 latency) -> vmcnt(0)+barrier. No register staging left
//     to be collapsed by the compiler (the round-5 lesson).
//   * Swapped QK^T (full P-row per lane), lane-local softmax, PV A-frags
//     via 16 __shfl + selects; setprio around MFMA clusters; CHUNK=16
//     split-K with fp32 atomic partials.
// ---------------------------------------------------------------------------
__global__ __launch_bounds__(256, 4) void attn_kernel(
    const bf16* __restrict__ qkv, const bf16* __restrict__ vt,
    float* __restrict__ o_buf, float* __restrict__ l_buf)
{
    const int i = blockIdx.x;                 // q-tile (64 rows)
    const int c = blockIdx.y;                 // k-chunk
    const int b = blockIdx.z;
    const int ntiles = i + 1;
    const int tile0  = c * CHUNK;
    if (tile0 >= ntiles) return;
    const int tile1 = min(tile0 + CHUNK, ntiles);

    // [pipe][row][128B] tiles, XOR-swizzled image; 16 KB each, 32 KB total
    __shared__ __align__(16) char KsB[2 * 64 * 128];
    __shared__ __align__(16) char VsB[2 * 64 * 128];

    auto kaddr = [](char* base, int pp, int row, int colb) -> void* {
        return base + pp * 8192 + row * 128 + (colb ^ ((row & 7) << 4));
    };

    const bf16* Q = qkv;
    const bf16* K = qkv + (size_t)M_TOT * D_HEAD;

    const int t    = threadIdx.x;
    const int wv   = t >> 6;
    const int lane = t & 63;
    const int quad = lane >> 4;
    const int l15  = lane & 15;
    const int qb   = i * 64;
    const size_t base  = (size_t)b * SEQ * D_HEAD;
    const bf16* vtb = vt + (size_t)b * D_HEAD * SEQ;

    bf16x8 qf0, qf1;
    {
        const bf16* qr = Q + base + (size_t)(qb + wv * 16 + l15) * D_HEAD;
        qf0 = *(const bf16x8*)(qr + quad * 8);
        qf1 = *(const bf16x8*)(qr + 32 + quad * 8);
    }

    f32x4 o[4] = {};
    float lsum = 0.f;                 // partial l for q = qw0+l15
    const int qw0 = qb + wv * 16;

    // ---- DMA staging: wave wv covers segments s = wv*2 + i of each tile.
    // Dest byte s*1024 + lane*16 -> LDS row rr = s*8 + (lane>>3),
    // col cc = (lane&7)*16; source col = cc ^ ((rr&7)<<4) so the LDS image
    // matches the old swizzled store exactly.
    const char* Kb = (const char*)(K + base);
    const char* Vb = (const char*)vtb;

    auto stage_kv = [&](int tile, int pp) {
        #pragma unroll
        for (int i2 = 0; i2 < 2; i2++) {
            const int s  = wv * 2 + i2;
            const int rr = s * 8 + (lane >> 3);       // row within tile
            const int sw = ((lane & 7) * 16) ^ ((lane >> 3) << 4);
            gld16(Kb + (size_t)(tile * 64 + rr) * 128 + sw,
                  KsB + pp * 8192 + s * 1024);
            gld16(Vb + (size_t)rr * (SEQ * 2) + (size_t)tile * 128 + sw,
                  VsB + pp * 8192 + s * 1024);
        }
    };

    // prologue: stage tile0 into pipe 0
    stage_kv(tile0, 0);
    phase_barrier();                  // pipe 0 staged

    int p = 0;
    for (int tile = tile0; tile < tile1; tile++) {
        const int kk0 = tile * 64;

        // issue next tile's DMAs first; they drain at the end-of-iter barrier
        if (tile + 1 < tile1) stage_kv(tile + 1, p ^ 1);

        // S^T = mfma(K, Q): D col = l15 = q, row = quad*4+r = key-sub
        f32x4 sc4[4];
        __builtin_amdgcn_s_setprio(1);
        #pragma unroll
        for (int kt = 0; kt < 4; kt++) {
            f32x4 z = {};
            z = MFMA(*(bf16x8*)kaddr(KsB, p, kt * 16 + l15, quad * 16),      qf0, z);
            z = MFMA(*(bf16x8*)kaddr(KsB, p, kt * 16 + l15, 64 + quad * 16), qf1, z);
            sc4[kt] = z;
        }
        __builtin_amdgcn_s_setprio(0);

        // lane-local softmax: this lane's 16 values belong to q = qw0+l15,
        // keys = kk0 + kt*16 + quad*4 + r
        bf16 ph[4][4];
        if (tile == i) {
            #pragma unroll
            for (int kt = 0; kt < 4; kt++)
                #pragma unroll
                for (int r = 0; r < 4; r++) {
                    float s = sc4[kt][r];
                    if (kk0 + kt * 16 + quad * 4 + r > qw0 + l15)
                        s = -1e30f;               // exp2 -> exactly 0
                    float pe = __builtin_amdgcn_exp2f(fmaf(s, LOG2E, -MFIX_L2));
                    lsum += pe;
                    ph[kt][r] = (bf16)pe;
                }
        } else {
            #pragma unroll
            for (int kt = 0; kt < 4; kt++)
                #pragma unroll
                for (int r = 0; r < 4; r++) {
                    float pe = __builtin_amdgcn_exp2f(
                        fmaf(sc4[kt][r], LOG2E, -MFIX_L2));
                    lsum += pe;
                    ph[kt][r] = (bf16)pe;
                }
        }

        // pack each kt's 4 bf16 into 2 dwords
        unsigned pku[4][2];
        #pragma unroll
        for (int kt = 0; kt < 4; kt++) {
            __builtin_memcpy(&pku[kt][0], &ph[kt][0], 4);
            __builtin_memcpy(&pku[kt][1], &ph[kt][2], 4);
        }

        // cross-quad exchange -> PV A-frags, then O += P V from Vs[p]
        const int srcA = l15 + ((lane & 16) ? 32 : 0);   // quad 2(qt&1)
        const int srcB = srcA + 16;                      // quad 2(qt&1)+1
        const bool hi  = (lane & 32) != 0;               // kt select = qt>>1

        #pragma unroll
        for (int c2 = 0; c2 < 2; c2++) {
            unsigned xA0 = __shfl((int)pku[2 * c2][0],     srcA);
            unsigned xA1 = __shfl((int)pku[2 * c2][1],     srcA);
            unsigned yA0 = __shfl((int)pku[2 * c2 + 1][0], srcA);
            unsigned yA1 = __shfl((int)pku[2 * c2 + 1][1], srcA);
            unsigned xB0 = __shfl((int)pku[2 * c2][0],     srcB);
            unsigned xB1 = __shfl((int)pku[2 * c2][1],     srcB);
            unsigned yB0 = __shfl((int)pku[2 * c2 + 1][0], srcB);
            unsigned yB1 = __shfl((int)pku[2 * c2 + 1][1], srcB);
            unsigned fr[4];
            fr[0] = hi ? yA0 : xA0;
            fr[1] = hi ? yA1 : xA1;
            fr[2] = hi ? yB0 : xB0;
            fr[3] = hi ? yB1 : xB1;
            bf16x8 pa;
            __builtin_memcpy(&pa, fr, 16);

            __builtin_amdgcn_s_setprio(1);
            #pragma unroll
            for (int t4 = 0; t4 < 4; t4++) {
                bf16x8 vb = *(bf16x8*)kaddr(VsB, p, t4 * 16 + l15,
                                            c2 * 64 + quad * 16);
                o[t4] = MFMA(pa, vb, o[t4]);
            }
            __builtin_amdgcn_s_setprio(0);
        }

        // end-of-tile: drain the next tile's DMAs + release this buffer.
        // All readers of buf p passed this barrier before p is restaged
        // (two tiles later) -> WAR-safe.
        if (tile + 1 < tile1) phase_barrier();
        p ^= 1;
    }

    // epilogue: l(q) = sum over the 4 quads sharing q = l15; atomic partials
    const int mrow0 = b * SEQ + qw0;
    lsum += __shfl_xor(lsum, 16, 64);
    lsum += __shfl_xor(lsum, 32, 64);
    if (lane < 16)
        atomicAdd(&l_buf[mrow0 + l15], lsum);
    #pragma unroll
    for (int r = 0; r < 4; r++) {
        const size_t orow = (size_t)(mrow0 + quad * 4 + r) * D_HEAD;
        #pragma unroll
        for (int t4 = 0; t4 < 4; t4++)
            atomicAdd(&o_buf[orow + t4 * 16 + l15], o[t4][r]);
    }
}

// ---------------------------------------------------------------------------
// out = o_buf / l_buf (fp32 output).
// ---------------------------------------------------------------------------
__global__ void norm_kernel(const float4* __restrict__ o_buf,
                            const float* __restrict__ l_buf,
                            float4* __restrict__ out)
{
    int gid = blockIdx.x * 256 + threadIdx.x;      // 0 .. M_TOT*16-1
    int m = gid >> 4;
    float inv = 1.0f / l_buf[m];
    float4 v = o_buf[gid];
    out[gid] = float4{v.x * inv, v.y * inv, v.z * inv, v.w * inv};
}

extern "C" void kernel_launch(void* const* d_in, const int* in_sizes, int n_in,
                              void* d_out, int out_size, void* d_ws, size_t ws_size,
                              hipStream_t stream) {
    const float* x  = (const float*)d_in[0];
    const float* Wq = (const float*)d_in[1];
    const float* Wk = (const float*)d_in[2];
    const float* Wv = (const float*)d_in[3];

    bf16*  qkv   = (bf16*)((char*)d_ws + QKV_OFF);
    float* o_buf = (float*)((char*)d_ws + OBUF_OFF);
    float* l_buf = (float*)((char*)d_ws + LBUF_OFF);
    bf16*  Wt    = (bf16*)((char*)d_ws + WT_OFF);
    bf16*  vt    = (bf16*)((char*)d_ws + VT_OFF);

    const int zero4 = (M_TOT * 65) / 4;            // o_buf + l_buf contiguous
    const int zblocks = (zero4 + 255) / 256;       // 1040
    prep_kernel<<<48 + zblocks, 256, 0, stream>>>(Wq, Wk, Wv, Wt,
                                                  (float4*)o_buf, zero4);
    proj_kernel<<<M_TOT / 32, 256, 0, stream>>>(x, Wt, qkv, vt);
    attn_kernel<<<dim3(SEQ / 64, SEQ / 64 / CHUNK, BATCH), 256, 0, stream>>>(
        qkv, vt, o_buf, l_buf);
    norm_kernel<<<M_TOT * 16 / 256, 256, 0, stream>>>((const float4*)o_buf, l_buf,
                                                      (float4*)d_out);
}

// Round 8
// 149.663 us; speedup vs baseline: 1.0084x; 1.0084x over previous
//
#include <hip/hip_runtime.h>

#define D_MODEL 1024
#define D_HEAD  64
#define SEQ     4096
#define BATCH   4
#define M_TOT   (BATCH * SEQ)          // 16384
#define LOG2E   1.44269504088896f
#define MFIX_L2 17.3123404906676f      // 12.0 * log2(e) — fixed softmax max
#define CHUNK   16                     // k-tiles per attn block

typedef __bf16 bf16;
typedef bf16  bf16x8 __attribute__((ext_vector_type(8)));
typedef bf16  bf16x4v __attribute__((ext_vector_type(4)));
typedef float f32x4  __attribute__((ext_vector_type(4)));

#define MFMA(a, b, c) __builtin_amdgcn_mfma_f32_16x16x32_bf16(a, b, c, 0, 0, 0)

// Counted-vmcnt phase barrier (T4): wait until only the newest N VMEM ops
// remain in flight (N = the NEXT tile's DMAs), then barrier. The DMA queue
// is never drained to 0 inside a loop — loads span ~2 phases. rule-#18
// sched_barrier fences stop hipcc hoisting ds_reads across it.
#define WAIT_BARRIER(N) do {                                       \
    __builtin_amdgcn_sched_barrier(0);                             \
    asm volatile("s_waitcnt vmcnt(" #N ")" ::: "memory");          \
    __builtin_amdgcn_s_barrier();                                  \
    __builtin_amdgcn_sched_barrier(0);                             \
} while (0)

// global -> LDS DMA, 16 bytes per lane. Dest is wave-uniform base + lane*16
// (linear); per-lane GLOBAL address carries any swizzle (m173 pattern).
__device__ __forceinline__ void gld16(const void* g, void* l) {
    __builtin_amdgcn_global_load_lds(
        (const __attribute__((address_space(1))) void*)g,
        (__attribute__((address_space(3))) void*)l, 16, 0, 0);
}

// Workspace layout (bytes):
//   qkv   bf16 [3][M_TOT][64]   @ 0         (6,291,456)  (V section unused)
//   o_buf f32  [M_TOT][64]      @ 6291456   (4,194,304)
//   l_buf f32  [M_TOT]          @ 10485760  (65,536)
//   Wt    bf16 [3][64][1024]    @ 10551296  (393,216)
//   vt    bf16 [B][64][SEQ]     @ 10944512  (2,097,152)   V transposed
#define QKV_OFF  0
#define OBUF_OFF 6291456
#define LBUF_OFF 10485760
#define WT_OFF   10551296
#define VT_OFF   10944512

// ---------------------------------------------------------------------------
// Prep. Blocks 0..47: transpose+cast W (fp32 [1024][64]) -> Wt (bf16
// [wm*64+n][1024]) via LDS tile. Blocks 48..: zero o_buf + l_buf.
// ---------------------------------------------------------------------------
__global__ void prep_kernel(const float* __restrict__ Wq, const float* __restrict__ Wk,
                            const float* __restrict__ Wv, bf16* __restrict__ Wt,
                            float4* __restrict__ zp, int n4)
{
    const int bx = blockIdx.x;
    const int t  = threadIdx.x;
    if (bx < 48) {
        __shared__ bf16 tr[64][72];                    // [n][k] tile, padded
        const int wm = bx >> 4, kt = bx & 15, k0 = kt * 64;
        const float* W = (wm == 0) ? Wq : (wm == 1) ? Wk : Wv;
        const int kr = t >> 2, nb = (t & 3) * 16;
        #pragma unroll
        for (int j = 0; j < 4; j++) {
            float4 wrow = *(const float4*)(W + (size_t)(k0 + kr) * D_HEAD + nb + j * 4);
            tr[nb + j * 4 + 0][kr] = (bf16)wrow.x;
            tr[nb + j * 4 + 1][kr] = (bf16)wrow.y;
            tr[nb + j * 4 + 2][kr] = (bf16)wrow.z;
            tr[nb + j * 4 + 3][kr] = (bf16)wrow.w;
        }
        __syncthreads();
        const int n = t >> 2, kc = (t & 3) * 8;
        bf16* dst = Wt + (size_t)(wm * 64 + n) * D_MODEL + k0;
        #pragma unroll
        for (int h = 0; h < 2; h++) {
            bf16x8 v;
            #pragma unroll
            for (int j = 0; j < 8; j++) v[j] = tr[n][kc + h * 32 + j];
            *(bf16x8*)(dst + kc + h * 32) = v;
        }
    } else {
        int i = (bx - 48) * 256 + t;
        if (i < n4) zp[i] = float4{0.f, 0.f, 0.f, 0.f};
    }
}

// ---------------------------------------------------------------------------
// Fused QKV projection v12 = v11 + T4 counted vmcnt + triple buffer + 8 waves.
// Round-7 ledger: proj ~33 µs vs 10.2 µs x-read floor. v11's vmcnt(0) drain
// per step exposed HBM latency (~900cy) minus one compute phase (~300cy)
// every step. v12: 512 thr (8 waves, BM=64, BN=192, BK=64), grid 256
// (1 block/CU), LDS 120 KB = 3 buffers; per step per wave 5 DMAs (2 A + 3 B).
// Top of step s: wait vmcnt(5) (step s done, s+1 in flight) -> barrier ->
// issue step s+2 -> compute. Each DMA gets ~2 compute phases of flight;
// vmcnt(0) only at the last step. Swizzle identical to v11 (verified R6).
// ---------------------------------------------------------------------------
__global__ __launch_bounds__(512, 1) void proj_kernel(
    const float* __restrict__ x, const bf16* __restrict__ Wt,
    bf16* __restrict__ qkv, bf16* __restrict__ vt)
{
    __shared__ __align__(16) char Al[3][64 * 256];   // fp32 [64 r][256 B] x3 = 48 KB
    __shared__ __align__(16) char Bl[3][192 * 128];  // bf16 [192 n][128 B] x3 = 72 KB

    const int t    = threadIdx.x;
    const int w    = t >> 6;            // wave 0..7
    const int rg2  = w >> 2;            // row half (32 rows)
    const int nw   = w & 3;             // col group (48 cols)
    const int lane = t & 63;
    const int quad = lane >> 4;
    const int l15  = lane & 15;
    const int row0 = blockIdx.x * 64;

    const char* xb = (const char*)x;
    const char* wb = (const char*)Wt;

    f32x4 acc[6] = {};                  // acc[rg*3+j]

    // ---- DMA staging (linear dest, swizzled source; 5 gld16/wave/step) ----
    auto stageA = [&](int bsel, int step) {
        #pragma unroll
        for (int i = 0; i < 2; i++) {
            const int s  = w * 2 + i;           // seg 0..15 (4 rows x 256 B)
            const int r  = s * 4 + (lane >> 4);
            const int cs = ((lane & 15) * 16) ^ ((r & 7) << 4);
            gld16(xb + (size_t)(row0 + r) * 4096 + step * 256 + cs,
                  (char*)Al[bsel] + s * 1024);
        }
    };
    auto stageB = [&](int bsel, int step) {
        #pragma unroll
        for (int i = 0; i < 3; i++) {
            const int s  = w * 3 + i;           // seg 0..23 (8 rows x 128 B)
            const int n  = s * 8 + (lane >> 3);
            const int cs = ((lane & 7) * 16) ^ ((n & 7) << 4);
            gld16(wb + (size_t)n * 2048 + step * 128 + cs,
                  (char*)Bl[bsel] + s * 1024);
        }
    };

    auto cvt8 = [](float4 lo, float4 hi) {
        bf16x8 r;
        r[0] = (bf16)lo.x; r[1] = (bf16)lo.y; r[2] = (bf16)lo.z; r[3] = (bf16)lo.w;
        r[4] = (bf16)hi.x; r[5] = (bf16)hi.y; r[6] = (bf16)hi.z; r[7] = (bf16)hi.w;
        return r;
    };

    // ---- compute one BK=64 tile from LDS buffer bsel ----
    auto compute = [&](int bsel) {
        const char* Ab = Al[bsel];
        const char* Bb = Bl[bsel];
        #pragma unroll
        for (int ks = 0; ks < 2; ks++) {        // two K=32 slices
            bf16x8 afr[2];
            #pragma unroll
            for (int rg = 0; rg < 2; rg++) {
                const int r  = rg2 * 32 + rg * 16 + l15;
                const int o  = ks * 128 + quad * 32;
                const int m  = (r & 7) << 4;
                float4 lo = *(const float4*)(Ab + r * 256 + (o ^ m));
                float4 hi = *(const float4*)(Ab + r * 256 + ((o + 16) ^ m));
                afr[rg] = cvt8(lo, hi);
            }
            #pragma unroll
            for (int j = 0; j < 3; j++) {
                const int n  = nw * 48 + j * 16 + l15;
                const int o  = ks * 64 + quad * 16;
                bf16x8 bfrg = *(const bf16x8*)(Bb + n * 128 + (o ^ ((n & 7) << 4)));
                acc[j]     = MFMA(afr[0], bfrg, acc[j]);
                acc[3 + j] = MFMA(afr[1], bfrg, acc[3 + j]);
            }
        }
    };

    // ---- T4 pipeline: 16 steps of BK=64, 2 staged ahead, counted waits ----
    stageA(0, 0); stageB(0, 0);
    stageA(1, 1); stageB(1, 1);

    int buf = 0;
    for (int s = 0; s < 16; s++) {
        if (s + 1 < 16) { WAIT_BARRIER(5); }   // step s done; s+1 in flight
        else            { WAIT_BARRIER(0); }   // final drain
        if (s + 2 < 16) {
            int nb2 = buf + 2; if (nb2 >= 3) nb2 -= 3;
            stageA(nb2, s + 2); stageB(nb2, s + 2);   // ~2 phases of flight
        }
        compute(buf);
        buf = (buf == 2) ? 0 : buf + 1;
    }

    // epilogue (v8-verified mapping): C row = quad*4+r within 16-row frag,
    // col = l15 within 16-col frag.
    const int bb = row0 >> 12, s0v = row0 & (SEQ - 1);
    const int rbase = rg2 * 32;
    #pragma unroll
    for (int rg = 0; rg < 2; rg++)
        #pragma unroll
        for (int j = 0; j < 3; j++) {
            const int col = nw * 48 + j * 16 + l15;   // wm uniform per (nw,j)
            const int wm = col >> 6, h = col & 63;
            if (wm == 2) {
                bf16x4v vv;
                #pragma unroll
                for (int r = 0; r < 4; r++)
                    vv[r] = (bf16)acc[rg * 3 + j][r];
                *(bf16x4v*)(vt + ((size_t)bb * D_HEAD + h) * SEQ +
                            s0v + rbase + rg * 16 + quad * 4) = vv;
            } else {
                const float sc = (wm == 0) ? 0.125f : 1.0f;
                bf16* outp = qkv + (size_t)wm * M_TOT * D_HEAD;
                #pragma unroll
                for (int r = 0; r < 4; r++) {
                    const int row = row0 + rbase + rg * 16 + quad * 4 + r;
                    outp[(size_t)row * D_HEAD + h] =
                        (bf16)(acc[rg * 3 + j][r] * sc);
                }
            }
        }
}

// ---------------------------------------------------------------------------
// Split-K causal flash attention v8 = v7 + T4 counted vmcnt + triple buffer.
// The per-tile vmcnt(0) drain is gone: top of tile t waits vmcnt(4) (tile
// t's 4 DMAs done; t+1's stay in flight), barrier, then issues tile t+2's
// DMAs -> ~2 tiles of flight. vmcnt(0) only on the last tile. LDS 48 KB
// (3 blocks/CU). LDS image & all fragment reads unchanged (R6/R7-verified).
// ---------------------------------------------------------------------------
__global__ __launch_bounds__(256, 3) void attn_kernel(
    const bf16* __restrict__ qkv, const bf16* __restrict__ vt,
    float* __restrict__ o_buf, float* __restrict__ l_buf)
{
    const int i = blockIdx.x;                 // q-tile (64 rows)
    const int c = blockIdx.y;                 // k-chunk
    const int b = blockIdx.z;
    const int ntiles = i + 1;
    const int tile0  = c * CHUNK;
    if (tile0 >= ntiles) return;
    const int tile1 = min(tile0 + CHUNK, ntiles);

    // [pipe][row][128B] tiles, XOR-swizzled image; 8 KB each, 3 pipes
    __shared__ __align__(16) char KsB[3 * 64 * 128];
    __shared__ __align__(16) char VsB[3 * 64 * 128];

    auto kaddr = [](char* base, int pp, int row, int colb) -> void* {
        return base + pp * 8192 + row * 128 + (colb ^ ((row & 7) << 4));
    };

    const bf16* Q = qkv;
    const bf16* K = qkv + (size_t)M_TOT * D_HEAD;

    const int t    = threadIdx.x;
    const int wv   = t >> 6;
    const int lane = t & 63;
    const int quad = lane >> 4;
    const int l15  = lane & 15;
    const int qb   = i * 64;
    const size_t base  = (size_t)b * SEQ * D_HEAD;
    const bf16* vtb = vt + (size_t)b * D_HEAD * SEQ;

    bf16x8 qf0, qf1;
    {
        const bf16* qr = Q + base + (size_t)(qb + wv * 16 + l15) * D_HEAD;
        qf0 = *(const bf16x8*)(qr + quad * 8);
        qf1 = *(const bf16x8*)(qr + 32 + quad * 8);
    }

    f32x4 o[4] = {};
    float lsum = 0.f;                 // partial l for q = qw0+l15
    const int qw0 = qb + wv * 16;

    // ---- DMA staging: wave wv covers segments s = wv*2 + i of each tile.
    // Dest byte s*1024 + lane*16 -> LDS row rr = s*8 + (lane>>3),
    // col cc = (lane&7)*16; source col = cc ^ ((rr&7)<<4) so the LDS image
    // matches the swizzled layout exactly. 4 gld16/wave/tile.
    const char* Kb = (const char*)(K + base);
    const char* Vb = (const char*)vtb;

    auto stage_kv = [&](int tile, int pp) {
        #pragma unroll
        for (int i2 = 0; i2 < 2; i2++) {
            const int s  = wv * 2 + i2;
            const int rr = s * 8 + (lane >> 3);       // row within tile
            const int sw = ((lane & 7) * 16) ^ ((lane >> 3) << 4);
            gld16(Kb + (size_t)(tile * 64 + rr) * 128 + sw,
                  KsB + pp * 8192 + s * 1024);
            gld16(Vb + (size_t)rr * (SEQ * 2) + (size_t)tile * 128 + sw,
                  VsB + pp * 8192 + s * 1024);
        }
    };

    // prologue: stage tile0 -> pipe 0, tile0+1 -> pipe 1
    stage_kv(tile0, 0);
    if (tile0 + 1 < tile1) stage_kv(tile0 + 1, 1);

    int p = 0;
    for (int tile = tile0; tile < tile1; tile++) {
        const int kk0 = tile * 64;

        // counted wait: tile t's 4 DMAs complete; t+1's stay in flight
        if (tile + 1 < tile1) { WAIT_BARRIER(4); }
        else                  { WAIT_BARRIER(0); }

        // issue tile t+2 into the third pipe (~2 tiles of flight);
        // WAR-safe: that pipe was read at iter t-1 and the barrier above
        // proves every wave finished those reads.
        if (tile + 2 < tile1) {
            int nb2 = p + 2; if (nb2 >= 3) nb2 -= 3;
            stage_kv(tile + 2, nb2);
        }

        // S^T = mfma(K, Q): D col = l15 = q, row = quad*4+r = key-sub
        f32x4 sc4[4];
        __builtin_amdgcn_s_setprio(1);
        #pragma unroll
        for (int kt = 0; kt < 4; kt++) {
            f32x4 z = {};
            z = MFMA(*(bf16x8*)kaddr(KsB, p, kt * 16 + l15, quad * 16),      qf0, z);
            z = MFMA(*(bf16x8*)kaddr(KsB, p, kt * 16 + l15, 64 + quad * 16), qf1, z);
            sc4[kt] = z;
        }
        __builtin_amdgcn_s_setprio(0);

        // lane-local softmax: this lane's 16 values belong to q = qw0+l15,
        // keys = kk0 + kt*16 + quad*4 + r
        bf16 ph[4][4];
        if (tile == i) {
            #pragma unroll
            for (int kt = 0; kt < 4; kt++)
                #pragma unroll
                for (int r = 0; r < 4; r++) {
                    float s = sc4[kt][r];
                    if (kk0 + kt * 16 + quad * 4 + r > qw0 + l15)
                        s = -1e30f;               // exp2 -> exactly 0
                    float pe = __builtin_amdgcn_exp2f(fmaf(s, LOG2E, -MFIX_L2));
                    lsum += pe;
                    ph[kt][r] = (bf16)pe;
                }
        } else {
            #pragma unroll
            for (int kt = 0; kt < 4; kt++)
                #pragma unroll
                for (int r = 0; r < 4; r++) {
                    float pe = __builtin_amdgcn_exp2f(
                        fmaf(sc4[kt][r], LOG2E, -MFIX_L2));
                    lsum += pe;
                    ph[kt][r] = (bf16)pe;
                }
        }

        // pack each kt's 4 bf16 into 2 dwords
        unsigned pku[4][2];
        #pragma unroll
        for (int kt = 0; kt < 4; kt++) {
            __builtin_memcpy(&pku[kt][0], &ph[kt][0], 4);
            __builtin_memcpy(&pku[kt][1], &ph[kt][2], 4);
        }

        // cross-quad exchange -> PV A-frags, then O += P V from Vs[p]
        const int srcA = l15 + ((lane & 16) ? 32 : 0);   // quad 2(qt&1)
        const int srcB = srcA + 16;                      // quad 2(qt&1)+1
        const bool hi  = (lane & 32) != 0;               // kt select = qt>>1

        #pragma unroll
        for (int c2 = 0; c2 < 2; c2++) {
            unsigned xA0 = __shfl((int)pku[2 * c2][0],     srcA);
            unsigned xA1 = __shfl((int)pku[2 * c2][1],     srcA);
            unsigned yA0 = __shfl((int)pku[2 * c2 + 1][0], srcA);
            unsigned yA1 = __shfl((int)pku[2 * c2 + 1][1], srcA);
            unsigned xB0 = __shfl((int)pku[2 * c2][0],     srcB);
            unsigned xB1 = __shfl((int)pku[2 * c2][1],     srcB);
            unsigned yB0 = __shfl((int)pku[2 * c2 + 1][0], srcB);
            unsigned yB1 = __shfl((int)pku[2 * c2 + 1][1], srcB);
            unsigned fr[4];
            fr[0] = hi ? yA0 : xA0;
            fr[1] = hi ? yA1 : xA1;
            fr[2] = hi ? yB0 : xB0;
            fr[3] = hi ? yB1 : xB1;
            bf16x8 pa;
            __builtin_memcpy(&pa, fr, 16);

            __builtin_amdgcn_s_setprio(1);
            #pragma unroll
            for (int t4 = 0; t4 < 4; t4++) {
                bf16x8 vb = *(bf16x8*)kaddr(VsB, p, t4 * 16 + l15,
                                            c2 * 64 + quad * 16);
                o[t4] = MFMA(pa, vb, o[t4]);
            }
            __builtin_amdgcn_s_setprio(0);
        }

        p = (p == 2) ? 0 : p + 1;
    }

    // epilogue: l(q) = sum over the 4 quads sharing q = l15; atomic partials
    const int mrow0 = b * SEQ + qw0;
    lsum += __shfl_xor(lsum, 16, 64);
    lsum += __shfl_xor(lsum, 32, 64);
    if (lane < 16)
        atomicAdd(&l_buf[mrow0 + l15], lsum);
    #pragma unroll
    for (int r = 0; r < 4; r++) {
        const size_t orow = (size_t)(mrow0 + quad * 4 + r) * D_HEAD;
        #pragma unroll
        for (int t4 = 0; t4 < 4; t4++)
            atomicAdd(&o_buf[orow + t4 * 16 + l15], o[t4][r]);
    }
}

// ---------------------------------------------------------------------------
// out = o_buf / l_buf (fp32 output).
// ---------------------------------------------------------------------------
__global__ void norm_kernel(const float4* __restrict__ o_buf,
                            const float* __restrict__ l_buf,
                            float4* __restrict__ out)
{
    int gid = blockIdx.x * 256 + threadIdx.x;      // 0 .. M_TOT*16-1
    int m = gid >> 4;
    float inv = 1.0f / l_buf[m];
    float4 v = o_buf[gid];
    out[gid] = float4{v.x * inv, v.y * inv, v.z * inv, v.w * inv};
}

extern "C" void kernel_launch(void* const* d_in, const int* in_sizes, int n_in,
                              void* d_out, int out_size, void* d_ws, size_t ws_size,
                              hipStream_t stream) {
    const float* x  = (const float*)d_in[0];
    const float* Wq = (const float*)d_in[1];
    const float* Wk = (const float*)d_in[2];
    const float* Wv = (const float*)d_in[3];

    bf16*  qkv   = (bf16*)((char*)d_ws + QKV_OFF);
    float* o_buf = (float*)((char*)d_ws + OBUF_OFF);
    float* l_buf = (float*)((char*)d_ws + LBUF_OFF);
    bf16*  Wt    = (bf16*)((char*)d_ws + WT_OFF);
    bf16*  vt    = (bf16*)((char*)d_ws + VT_OFF);

    const int zero4 = (M_TOT * 65) / 4;            // o_buf + l_buf contiguous
    const int zblocks = (zero4 + 255) / 256;       // 1040
    prep_kernel<<<48 + zblocks, 256, 0, stream>>>(Wq, Wk, Wv, Wt,
                                                  (float4*)o_buf, zero4);
    proj_kernel<<<M_TOT / 64, 512, 0, stream>>>(x, Wt, qkv, vt);
    attn_kernel<<<dim3(SEQ / 64, SEQ / 64 / CHUNK, BATCH), 256, 0, stream>>>(
        qkv, vt, o_buf, l_buf);
    norm_kernel<<<M_TOT * 16 / 256, 256, 0, stream>>>((const float4*)o_buf, l_buf,
                                                      (float4*)d_out);
}